// Round 13
// baseline (74.404 us; speedup 1.0000x reference)
//
#include <hip/hip_runtime.h>

#define WAVE 64
#define TPB  256
#define SPB  4      // consecutive segments per block (one contiguous slab)
#define MAXP 1536   // max slab points staged in LDS (binomial: 4*256 mean, 16+ sigma)
#define F4MAX 1156  // ceil(3*MAXP/4)+pad
#define W4MAX 390   // ceil(MAXP/4)+pad

// DPP-fused butterfly stage (VALU pipe). ctrl must be a literal.
template <int CTRL>
__device__ __forceinline__ float dpp_f(float x) {
    int xi = __builtin_bit_cast(int, x);
    int r  = __builtin_amdgcn_update_dpp(xi, xi, CTRL, 0xF, 0xF, false);
    return __builtin_bit_cast(float, r);
}
#define DPP_XOR1 0xB1   // quad_perm [1,0,3,2]
#define DPP_XOR2 0x4E   // quad_perm [2,3,0,1]
#define DPP_XOR4 0x141  // row_half_mirror
#define DPP_XOR8 0x140  // row_mirror

__device__ __forceinline__ unsigned div3u(unsigned n) {
    return (unsigned)(((unsigned long long)n * 0xAAAAAAABull) >> 33);
}

// idx may be int32 (JAX default) or int64 (x64 enabled).
__global__ void detect_idx64(const unsigned int* __restrict__ w32, long long N,
                             int* __restrict__ flag) {
    long long base = (N / 2) | 1LL;
    long long stride = ((N / 2) / 64) & ~1LL;
    if (stride < 2) stride = 2;
    long long p = base + (long long)threadIdx.x * stride;
    unsigned int v = (p < N) ? w32[p] : 0u;
    unsigned long long nz = __ballot(v != 0u);
    if (threadIdx.x == 0) *flag = (nz == 0ULL) ? 1 : 0;   // 1 -> int64
}

__device__ __forceinline__ int load_idx(const void* __restrict__ p,
                                        long long i, int is64) {
    return is64 ? (int)((const long long*)p)[i] : ((const int*)p)[i];
}

// start[t] = lower_bound(idx, t), one binary search per boundary.
__global__ void find_bounds_bs(const void* __restrict__ idxp,
                               const int* __restrict__ flag,
                               int* __restrict__ start,
                               long long N, int S) {
    const int t = blockIdx.x * blockDim.x + threadIdx.x;
    if (t > S) return;
    const int is64 = *flag;
    long long lo = 0, hi = N;
    while (lo < hi) {
        long long mid = (lo + hi) >> 1;
        if (load_idx(idxp, mid, is64) < t) lo = mid + 1; else hi = mid;
    }
    start[t] = (int)lo;
}

// Slab-dense fused kernel. Block owns SPB consecutive segments = contiguous
// point range [p0,p1). Phase A: lane-dense float4 staging of pos+w into LDS
// (the fillBuffer-like pattern). Phase B: wave i reduces segment i from LDS
// (stride-3 scalar reads, conflict-free), DPP+shfl butterfly. Phase C: dense
// float4 normalized writes; per-component segment via magic-div3 + compares.
__global__ __launch_bounds__(TPB)
void seg_norm_dense(const float* __restrict__ pos,
                    const float* __restrict__ w,
                    const int* __restrict__ start,
                    float* __restrict__ out,
                    float* __restrict__ diam_out,
                    int S, long long N) {
    const int tid  = threadIdx.x;
    const int wid  = tid >> 6;
    const int lane = tid & 63;
    const int s0   = blockIdx.x * SPB;

    __shared__ int    sb[SPB + 1];
    __shared__ float4 sseg[SPB];
    __shared__ float4 ldsp4[F4MAX];
    __shared__ float4 ldsw4[W4MAX];

    if (tid <= SPB) {
        int k = s0 + tid;
        sb[tid] = start[k > S ? S : k];
    }
    __syncthreads();

    const int p0 = sb[0], p1 = sb[SPB];
    const bool useld = (p1 - p0) <= MAXP;
    const int F0 = (3 * p0) >> 2;            // first float4 of slab pos
    const int F1 = (3 * p1 + 3) >> 2;        // ceil
    const int W0 = p0 >> 2, W1 = (p1 + 3) >> 2;

    const float4* __restrict__ pos4 = (const float4*)pos;
    const float4* __restrict__ w4g  = (const float4*)w;
    float* ldsfw  = (float*)ldsp4;
    float* ldswfw = (float*)ldsw4;

    if (useld) {
        // ---- Phase A: dense streaming loads (lane stride 16 B) ----
        const int Ff = min(F1, (int)((3 * N) >> 2));
        for (int j = F0 + tid; j < Ff; j += TPB) ldsp4[j - F0] = pos4[j];
        for (int j = 4 * Ff + tid; j < 3 * p1; j += TPB)       // N%4 tail
            ldsfw[j - 4 * F0] = pos[j];
        const int Wf = min(W1, (int)(N >> 2));
        for (int j = W0 + tid; j < Wf; j += TPB) ldsw4[j - W0] = w4g[j];
        for (int j = 4 * Wf + tid; j < p1; j += TPB)
            ldswfw[j - 4 * W0] = w[j];
    }
    __syncthreads();

    const float* __restrict__ ldsf  = (const float*)ldsp4;
    const float* __restrict__ ldswf = (const float*)ldsw4;

    // ---- Phase B: per-wave segment reduction ----
    {
        const int s = s0 + wid;
        const int lo = sb[wid], hi = sb[wid + 1];

        float mnx = INFINITY,  mny = INFINITY,  mnz = INFINITY;
        float mxx = -INFINITY, mxy = -INFINITY, mxz = -INFINITY;
        float sw = 0.f, swx = 0.f, swy = 0.f, swz = 0.f;

        for (int p = lo + lane; p < hi; p += WAVE) {
            float x, y, z, ww;
            if (useld) {
                const int fb = 3 * p - 4 * F0;
                x = ldsf[fb]; y = ldsf[fb + 1]; z = ldsf[fb + 2];
                ww = ldswf[p - 4 * W0];
            } else {                                  // never-taken fallback
                x = pos[3LL * p]; y = pos[3LL * p + 1]; z = pos[3LL * p + 2];
                ww = w[p];
            }
            mnx = fminf(mnx, x); mxx = fmaxf(mxx, x);
            mny = fminf(mny, y); mxy = fmaxf(mxy, y);
            mnz = fminf(mnz, z); mxz = fmaxf(mxz, z);
            sw += ww;
            swx = fmaf(ww, x, swx);
            swy = fmaf(ww, y, swy);
            swz = fmaf(ww, z, swz);
        }

        #define ALLV(STAGEOP)                            \
            mnx = fminf(mnx, STAGEOP(mnx));              \
            mny = fminf(mny, STAGEOP(mny));              \
            mnz = fminf(mnz, STAGEOP(mnz));              \
            mxx = fmaxf(mxx, STAGEOP(mxx));              \
            mxy = fmaxf(mxy, STAGEOP(mxy));              \
            mxz = fmaxf(mxz, STAGEOP(mxz));              \
            sw  += STAGEOP(sw);                          \
            swx += STAGEOP(swx);                         \
            swy += STAGEOP(swy);                         \
            swz += STAGEOP(swz);
        #define ST_X1(v)  dpp_f<DPP_XOR1>(v)
        #define ST_X2(v)  dpp_f<DPP_XOR2>(v)
        #define ST_X4(v)  dpp_f<DPP_XOR4>(v)
        #define ST_X8(v)  dpp_f<DPP_XOR8>(v)
        #define ST_X16(v) __shfl_xor((v), 16)
        #define ST_X32(v) __shfl_xor((v), 32)
        ALLV(ST_X1) ALLV(ST_X2) ALLV(ST_X4) ALLV(ST_X8) ALLV(ST_X16) ALLV(ST_X32)
        #undef ST_X1
        #undef ST_X2
        #undef ST_X4
        #undef ST_X8
        #undef ST_X16
        #undef ST_X32
        #undef ALLV

        if (lane == 0 && s < S) {
            const float diam = fmaxf(mxx - mnx, fmaxf(mxy - mny, mxz - mnz));
            const float wsafe = (sw == 0.f) ? 1.f : sw;
            sseg[wid] = make_float4(swx / wsafe, swy / wsafe, swz / wsafe,
                                    1.f / (diam + 0.01f));
            diam_out[s] = diam;
        }
    }
    __syncthreads();

    // ---- Phase C: dense normalized writes ----
    const unsigned b1 = (unsigned)sb[1], b2 = (unsigned)sb[2],
                   b3 = (unsigned)sb[3];
    const int Q0 = (3 * p0 + 3) >> 2;        // first fully-owned out quad
    const int Q1 = (3 * p1) >> 2;            // exclusive
    float4* __restrict__ out4 = (float4*)out;

    for (int f = Q0 + tid; f < Q1; f += TPB) {
        const float4 q = useld ? ldsp4[f - F0] : pos4[f];
        float4 r;
        #pragma unroll
        for (int c = 0; c < 4; ++c) {
            const unsigned Fi = 4u * (unsigned)f + (unsigned)c;
            const unsigned pt = div3u(Fi);
            const int k = (int)(Fi - 3u * pt);
            const int sl = (pt >= b1) + (pt >= b2) + (pt >= b3);
            const float4 sg = sseg[sl];
            const float ctr = (k == 0) ? sg.x : ((k == 1) ? sg.y : sg.z);
            const float v = (c == 0) ? q.x : (c == 1) ? q.y : (c == 2) ? q.z : q.w;
            ((float*)&r)[c] = (v - ctr) * sg.w;
        }
        out4[f] = r;
    }

    // Edge floats not covered by full quads (<=3 each side of the slab).
    const int eL0 = 3 * p0;
    const int eL1 = min(4 * Q0, 3 * p1);
    const int eR0 = max(4 * Q1, 3 * p0);
    const int eR1 = 3 * p1;
    int Fi = -1;
    if (tid < eL1 - eL0)                 Fi = eL0 + tid;
    else if (tid >= 64 && tid - 64 < eR1 - eR0) Fi = eR0 + (tid - 64);
    if (Fi >= 0) {
        const unsigned pt = div3u((unsigned)Fi);
        const int k = (int)((unsigned)Fi - 3u * pt);
        const int sl = (pt >= b1) + (pt >= b2) + (pt >= b3);
        const float4 sg = sseg[sl];
        const float ctr = (k == 0) ? sg.x : ((k == 1) ? sg.y : sg.z);
        const float v = useld ? ldsf[Fi - 4 * F0] : pos[Fi];
        out[Fi] = (v - ctr) * sg.w;
    }
}

extern "C" void kernel_launch(void* const* d_in, const int* in_sizes, int n_in,
                              void* d_out, int out_size, void* d_ws, size_t ws_size,
                              hipStream_t stream) {
    const float* pos  = (const float*)d_in[0];
    const void*  idxp = d_in[1];
    const float* w    = (const float*)d_in[2];

    const long long N = (long long)in_sizes[0] / 3;     // 8388608
    const int S = out_size - in_sizes[0];               // 32768

    float* out = (float*)d_out;
    float* diam_out = out + (long long)in_sizes[0];     // tail of d_out

    int* flag  = (int*)d_ws;
    int* start = (int*)((char*)d_ws + 256);

    detect_idx64<<<1, 64, 0, stream>>>((const unsigned int*)idxp, N, flag);

    find_bounds_bs<<<(S + 1 + 63) / 64, 64, 0, stream>>>(idxp, flag, start, N, S);

    seg_norm_dense<<<(S + SPB - 1) / SPB, TPB, 0, stream>>>(
        pos, w, start, out, diam_out, S, N);
}